// Round 7
// baseline (353.781 us; speedup 1.0000x reference)
//
#include <hip/hip_runtime.h>

typedef unsigned short u16;
typedef u16 u16x8 __attribute__((ext_vector_type(8)));
typedef __bf16 bf16x8 __attribute__((ext_vector_type(8)));
typedef float f32x4 __attribute__((ext_vector_type(4)));

#define NE 8

// ---- helpers ----
__device__ __forceinline__ unsigned pk2(float a, float b) {
  unsigned ua = __builtin_bit_cast(unsigned, a) + 0x8000u;
  unsigned ub = __builtin_bit_cast(unsigned, b) + 0x8000u;
  return __builtin_amdgcn_perm(ub, ua, 0x07060302);
}
__device__ __forceinline__ u16 f2bf(float f) {
  return (u16)((__builtin_bit_cast(unsigned, f) + 0x8000u) >> 16);
}
__device__ __forceinline__ bf16x8 ldfrag(const u16* p) {
  union { u16x8 u; bf16x8 b; } x;
  x.u = *(const u16x8*)p;
  return x.b;
}
// async global->LDS, 16 B/lane: HW writes lane l at (uniform lds base) + l*16
__device__ __forceinline__ void gld16(const void* g, void* l) {
  __builtin_amdgcn_global_load_lds(
      (const __attribute__((address_space(1))) unsigned int*)g,
      (__attribute__((address_space(3))) unsigned int*)l, 16, 0, 0);
}
#define MFMA16 __builtin_amdgcn_mfma_f32_16x16x32_bf16

// ---- fused routing + x->bf16 prep ----
__global__ __launch_bounds__(64) void route_prep_kernel(
    const float* __restrict__ x, const float* __restrict__ gw,
    const float* __restrict__ segw, int* __restrict__ counts,
    int* __restrict__ ptok, float* __restrict__ pw, float* __restrict__ sgate,
    u16* __restrict__ xb) {
  int t = blockIdx.x;
  int lane = threadIdx.x;
  const float* xr = x + (size_t)t * 2048;
  u16* xbr = xb + (size_t)t * 2048;
  float s[NE];
#pragma unroll
  for (int e = 0; e < NE; e++) s[e] = 0.f;
  float sg = 0.f;
#pragma unroll
  for (int it = 0; it < 8; it++) {
    int c = it * 256 + lane * 4;
    f32x4 xv = *(const f32x4*)(xr + c);
    *(uint2*)(xbr + c) = make_uint2(pk2(xv[0], xv[1]), pk2(xv[2], xv[3]));
#pragma unroll
    for (int e = 0; e < NE; e++) {
      f32x4 wv4 = *(const f32x4*)(gw + e * 2048 + c);
      s[e] += xv[0] * wv4[0] + xv[1] * wv4[1] + xv[2] * wv4[2] + xv[3] * wv4[3];
    }
    f32x4 sv = *(const f32x4*)(segw + c);
    sg += xv[0] * sv[0] + xv[1] * sv[1] + xv[2] * sv[2] + xv[3] * sv[3];
  }
#pragma unroll
  for (int off = 32; off > 0; off >>= 1) {
#pragma unroll
    for (int e = 0; e < NE; e++) s[e] += __shfl_down(s[e], off);
    sg += __shfl_down(sg, off);
  }
  if (lane == 0) {
    int i0 = 0;
#pragma unroll
    for (int e = 1; e < NE; e++) if (s[e] > s[i0]) i0 = e;
    int i1 = (i0 == 0) ? 1 : 0;
#pragma unroll
    for (int e = 0; e < NE; e++) if (e != i0 && s[e] > s[i1]) i1 = e;
    float r = __expf(s[i1] - s[i0]);
    float w0 = 1.f / (1.f + r);
    float w1 = 1.f - w0;
    int s0 = atomicAdd(&counts[i0], 1);
    ptok[(i0 << 9) + s0] = t; pw[(i0 << 9) + s0] = w0;
    int s1 = atomicAdd(&counts[i1], 1);
    ptok[(i1 << 9) + s1] = t; pw[(i1 << 9) + s1] = w1;
    sgate[t] = 1.f / (1.f + __expf(-sg));
  }
}

// ================= gateup: M=128, N=64 (32 gate + 32 up), BK=64 =============
// Depth-2 prefetch, 3 LDS buffers, counted vmcnt(8) (never drain in loop),
// one barrier per K-step. A bf16 via gld16 (swizzled global source);
// B fp32->regs->cvt->swizzled ds_write (write-late).
__global__ __launch_bounds__(256) void gateup_kernel(
    const u16* __restrict__ xb, const float* __restrict__ Wg,
    const float* __restrict__ Wu, const float* __restrict__ SWg,
    const float* __restrict__ SWu, u16* __restrict__ hbufB,
    u16* __restrict__ hsB, const int* __restrict__ ptok,
    const int* __restrict__ counts) {
  __shared__ __align__(16) u16 As[3 * 8192];  // 3 x 16 KB (128x64 bf16)
  __shared__ __align__(16) u16 Bs[3 * 4096];  // 3 x 8 KB  (64x64 bf16)

  int b = blockIdx.x;
  int t = threadIdx.x;
  int is_ex = (b < 1024);
  int e = 0, j, mt, cnt;
  const float *gW, *uW;
  u16* obase;
  if (is_ex) {
    e = b & 7; j = (b >> 3) & 31; mt = b >> 8;  // 8e x 32j x 4mt
    cnt = counts[e];
    if (mt * 128 >= cnt) return;
    gW = Wg + (size_t)(e * 1024 + j * 32) * 2048;
    uW = Wu + (size_t)(e * 1024 + j * 32) * 2048;
    obase = hbufB + (size_t)(e * 64 + 2 * j) * 8192;
  } else {
    // shared: 64j x 4mt, same-j pinned to one XCD
    int bs = b - 1024;
    int xcd = bs & 7; mt = (bs >> 3) & 3; j = (bs >> 5) * 8 + xcd; cnt = 512;
    gW = SWg + (size_t)(j * 32) * 2048;
    uW = SWu + (size_t)(j * 32) * 2048;
    obase = hsB + (size_t)(2 * j) * 8192;
  }

  int lane = t & 63, wv = t >> 6;
  int quad = lane >> 4, l16 = lane & 15;

  // A: 16 chunks of 8 rows x 128 B; wave wv stages chunks 4wv..4wv+3
  const u16* aptr[4];
  int aoff[4];
#pragma unroll
  for (int i = 0; i < 4; i++) {
    int c = 4 * wv + i;
    int row = 8 * c + (lane >> 3);
    int slot = mt * 128 + row;
    int tok = is_ex ? ((slot < cnt) ? ptok[(e << 9) + slot] : 0) : slot;
    aptr[i] = xb + (size_t)tok * 2048 + (((lane & 7) ^ ((lane >> 3) & 7)) * 8);
    aoff[i] = c * 512;
  }
  // B: 64 rows (32 gate + 32 up); thread stages 4 rows: rloc = wv*16+i*4+quad
  const float* bsrc[4];
  int bwr[4];
#pragma unroll
  for (int i = 0; i < 4; i++) {
    int rloc = wv * 16 + i * 4 + quad;
    const float* base = (rloc < 32) ? (gW + (size_t)rloc * 2048)
                                    : (uW + (size_t)(rloc - 32) * 2048);
    bsrc[i] = base + l16 * 4;
    bwr[i] = rloc * 64 + (((l16 >> 1) ^ (rloc & 7)) * 8) + ((l16 & 1) * 4);
  }

  f32x4 bA0, bA1, bA2, bA3, bB0, bB1, bB2, bB3;
  f32x4 acc00 = {}, acc01 = {}, acc02 = {}, acc03 = {};
  f32x4 acc10 = {}, acc11 = {}, acc12 = {}, acc13 = {};

#define GU_ISSUE(kt1, ao, S)                                                \
  S##0 = *(const f32x4*)(bsrc[0] + (kt1) * 64);                             \
  S##1 = *(const f32x4*)(bsrc[1] + (kt1) * 64);                             \
  S##2 = *(const f32x4*)(bsrc[2] + (kt1) * 64);                             \
  S##3 = *(const f32x4*)(bsrc[3] + (kt1) * 64);                             \
  gld16(aptr[0] + (kt1) * 64, &As[(ao) + aoff[0]]);                         \
  gld16(aptr[1] + (kt1) * 64, &As[(ao) + aoff[1]]);                         \
  gld16(aptr[2] + (kt1) * 64, &As[(ao) + aoff[2]]);                         \
  gld16(aptr[3] + (kt1) * 64, &As[(ao) + aoff[3]]);                         \
  __builtin_amdgcn_sched_barrier(0);

#define GU_WRITEB(ao, S)                                                    \
  *(uint2*)(&Bs[((ao) >> 1) + bwr[0]]) =                                    \
      make_uint2(pk2(S##0[0], S##0[1]), pk2(S##0[2], S##0[3]));             \
  *(uint2*)(&Bs[((ao) >> 1) + bwr[1]]) =                                    \
      make_uint2(pk2(S##1[0], S##1[1]), pk2(S##1[2], S##1[3]));             \
  *(uint2*)(&Bs[((ao) >> 1) + bwr[2]]) =                                    \
      make_uint2(pk2(S##2[0], S##2[1]), pk2(S##2[2], S##2[3]));             \
  *(uint2*)(&Bs[((ao) >> 1) + bwr[3]]) =                                    \
      make_uint2(pk2(S##3[0], S##3[1]), pk2(S##3[2], S##3[3]));

#define GU_COMPUTE(ao)                                                      \
  _Pragma("unroll") for (int k2 = 0; k2 < 2; k2++) {                        \
    int sl = ((k2 * 4 + quad) ^ (l16 & 7)) * 8;                             \
    bf16x8 af0 = ldfrag(&As[(ao) + (wv * 32 + l16) * 64 + sl]);             \
    bf16x8 af1 = ldfrag(&As[(ao) + (wv * 32 + 16 + l16) * 64 + sl]);        \
    bf16x8 bf0 = ldfrag(&Bs[((ao) >> 1) + l16 * 64 + sl]);                  \
    bf16x8 bf1 = ldfrag(&Bs[((ao) >> 1) + (16 + l16) * 64 + sl]);           \
    bf16x8 bf2 = ldfrag(&Bs[((ao) >> 1) + (32 + l16) * 64 + sl]);           \
    bf16x8 bf3 = ldfrag(&Bs[((ao) >> 1) + (48 + l16) * 64 + sl]);           \
    acc00 = MFMA16(af0, bf0, acc00, 0, 0, 0);                               \
    acc01 = MFMA16(af0, bf1, acc01, 0, 0, 0);                               \
    acc02 = MFMA16(af0, bf2, acc02, 0, 0, 0);                               \
    acc03 = MFMA16(af0, bf3, acc03, 0, 0, 0);                               \
    acc10 = MFMA16(af1, bf0, acc10, 0, 0, 0);                               \
    acc11 = MFMA16(af1, bf1, acc11, 0, 0, 0);                               \
    acc12 = MFMA16(af1, bf2, acc12, 0, 0, 0);                               \
    acc13 = MFMA16(af1, bf3, acc13, 0, 0, 0);                               \
  }

#define GU_PHASE(kt, aoC, aoI, aoW, Si, Sw)                                 \
  GU_ISSUE((kt) + 2, aoI, Si)                                               \
  GU_COMPUTE(aoC)                                                           \
  asm volatile("s_waitcnt vmcnt(8)" ::: "memory");                          \
  __builtin_amdgcn_sched_barrier(0);                                        \
  GU_WRITEB(aoW, Sw)                                                        \
  asm volatile("s_waitcnt lgkmcnt(0)" ::: "memory");                        \
  __builtin_amdgcn_s_barrier();                                             \
  __builtin_amdgcn_sched_barrier(0);

  int o0 = 0, o1 = 8192, o2 = 16384;
  GU_ISSUE(0, o0, bA)
  GU_ISSUE(1, o1, bB)
  asm volatile("s_waitcnt vmcnt(8)" ::: "memory");
  __builtin_amdgcn_sched_barrier(0);
  GU_WRITEB(o0, bA)
  asm volatile("s_waitcnt lgkmcnt(0)" ::: "memory");
  __builtin_amdgcn_s_barrier();
  __builtin_amdgcn_sched_barrier(0);

  for (int kt = 0; kt < 30; kt += 2) {
    GU_PHASE(kt, o0, o2, o1, bA, bB)
    GU_PHASE(kt + 1, o1, o0, o2, bB, bA)
    int tmp = o0; o0 = o2; o2 = o1; o1 = tmp;
  }
  // tail: T30 at o0 (T31 in flight), then T31
  GU_COMPUTE(o0)
  asm volatile("s_waitcnt vmcnt(0)" ::: "memory");
  __builtin_amdgcn_sched_barrier(0);
  GU_WRITEB(o1, bB)
  asm volatile("s_waitcnt lgkmcnt(0)" ::: "memory");
  __builtin_amdgcn_s_barrier();
  __builtin_amdgcn_sched_barrier(0);
  GU_COMPUTE(o1)
#undef GU_ISSUE
#undef GU_WRITEB
#undef GU_COMPUTE
#undef GU_PHASE

  // epilogue: h = silu(g)*u ; gate frag n pairs with up frag n+2
#define GU_EPI(AG, AU, i, n)                                                \
  _Pragma("unroll") for (int g = 0; g < 4; g++) {                           \
    int rloc = wv * 32 + (i) * 16 + quad * 4 + g;                           \
    int slot = mt * 128 + rloc;                                             \
    if (slot < cnt) {                                                       \
      float gv = AG[g], uv = AU[g];                                         \
      float h = gv / (1.f + __expf(-gv)) * uv;                              \
      obase[(size_t)(n) * 8192 + slot * 16 + l16] = f2bf(h);                \
    }                                                                       \
  }
  GU_EPI(acc00, acc02, 0, 0)
  GU_EPI(acc01, acc03, 0, 1)
  GU_EPI(acc10, acc12, 1, 0)
  GU_EPI(acc11, acc13, 1, 1)
#undef GU_EPI
}

// ============ merged down: expert [0,1024) M=128 N=64 K=1024, =============
// ============ shared [1024,1152) M=128 N=64 K=2048; same pipeline =========
__global__ __launch_bounds__(256) void down_kernel(
    const u16* __restrict__ hbufB, const u16* __restrict__ hsB,
    const float* __restrict__ Wd, const float* __restrict__ SWd,
    float* __restrict__ out, const int* __restrict__ ptok,
    const float* __restrict__ pw, const int* __restrict__ counts,
    const float* __restrict__ sgate) {
  __shared__ __align__(16) u16 As[3 * 8192];  // 3 x 16 KB (4 j16-groups)
  __shared__ __align__(16) u16 Bs[3 * 4096];  // 3 x 8 KB

  int b = blockIdx.x;
  int t = threadIdx.x;
  int lane = t & 63, wv = t >> 6;
  int quad = lane >> 4, l16 = lane & 15;

#define DN_ISSUE(kt1, ao, S)                                                \
  S##0 = *(const f32x4*)(bsrc[0] + (kt1) * 64);                             \
  S##1 = *(const f32x4*)(bsrc[1] + (kt1) * 64);                             \
  S##2 = *(const f32x4*)(bsrc[2] + (kt1) * 64);                             \
  S##3 = *(const f32x4*)(bsrc[3] + (kt1) * 64);                             \
  gld16(aptr[0] + (size_t)(kt1) * 32768, &As[(ao) + aoff[0]]);              \
  gld16(aptr[1] + (size_t)(kt1) * 32768, &As[(ao) + aoff[1]]);              \
  gld16(aptr[2] + (size_t)(kt1) * 32768, &As[(ao) + aoff[2]]);              \
  gld16(aptr[3] + (size_t)(kt1) * 32768, &As[(ao) + aoff[3]]);              \
  __builtin_amdgcn_sched_barrier(0);

#define DN_WRITEB(ao, S)                                                    \
  *(uint2*)(&Bs[((ao) >> 1) + bwr[0]]) =                                    \
      make_uint2(pk2(S##0[0], S##0[1]), pk2(S##0[2], S##0[3]));             \
  *(uint2*)(&Bs[((ao) >> 1) + bwr[1]]) =                                    \
      make_uint2(pk2(S##1[0], S##1[1]), pk2(S##1[2], S##1[3]));             \
  *(uint2*)(&Bs[((ao) >> 1) + bwr[2]]) =                                    \
      make_uint2(pk2(S##2[0], S##2[1]), pk2(S##2[2], S##2[3]));             \
  *(uint2*)(&Bs[((ao) >> 1) + bwr[3]]) =                                    \
      make_uint2(pk2(S##3[0], S##3[1]), pk2(S##3[2], S##3[3]));

#define DN_COMPUTE(ao)                                                      \
  _Pragma("unroll") for (int k2 = 0; k2 < 2; k2++) {                        \
    int jsec = (k2 * 2 + (quad >> 1)) * 2048 +                              \
               (((quad & 1) ^ ((l16 >> 2) & 1)) * 8);                       \
    int sl = ((k2 * 4 + quad) ^ (l16 & 7)) * 8;                             \
    bf16x8 af0 = ldfrag(&As[(ao) + jsec + (wv * 32 + l16) * 16]);           \
    bf16x8 af1 = ldfrag(&As[(ao) + jsec + (wv * 32 + 16 + l16) * 16]);      \
    bf16x8 bf0 = ldfrag(&Bs[((ao) >> 1) + l16 * 64 + sl]);                  \
    bf16x8 bf1 = ldfrag(&Bs[((ao) >> 1) + (16 + l16) * 64 + sl]);           \
    bf16x8 bf2 = ldfrag(&Bs[((ao) >> 1) + (32 + l16) * 64 + sl]);           \
    bf16x8 bf3 = ldfrag(&Bs[((ao) >> 1) + (48 + l16) * 64 + sl]);           \
    acc00 = MFMA16(af0, bf0, acc00, 0, 0, 0);                               \
    acc01 = MFMA16(af0, bf1, acc01, 0, 0, 0);                               \
    acc02 = MFMA16(af0, bf2, acc02, 0, 0, 0);                               \
    acc03 = MFMA16(af0, bf3, acc03, 0, 0, 0);                               \
    acc10 = MFMA16(af1, bf0, acc10, 0, 0, 0);                               \
    acc11 = MFMA16(af1, bf1, acc11, 0, 0, 0);                               \
    acc12 = MFMA16(af1, bf2, acc12, 0, 0, 0);                               \
    acc13 = MFMA16(af1, bf3, acc13, 0, 0, 0);                               \
  }

#define DN_PHASE(kt, aoC, aoI, aoW, Si, Sw)                                 \
  DN_ISSUE((kt) + 2, aoI, Si)                                               \
  DN_COMPUTE(aoC)                                                           \
  asm volatile("s_waitcnt vmcnt(8)" ::: "memory");                          \
  __builtin_amdgcn_sched_barrier(0);                                        \
  DN_WRITEB(aoW, Sw)                                                        \
  asm volatile("s_waitcnt lgkmcnt(0)" ::: "memory");                        \
  __builtin_amdgcn_s_barrier();                                             \
  __builtin_amdgcn_sched_barrier(0);

#define DN_PROLOGUE                                                         \
  DN_ISSUE(0, o0, bA)                                                       \
  DN_ISSUE(1, o1, bB)                                                       \
  asm volatile("s_waitcnt vmcnt(8)" ::: "memory");                          \
  __builtin_amdgcn_sched_barrier(0);                                        \
  DN_WRITEB(o0, bA)                                                         \
  asm volatile("s_waitcnt lgkmcnt(0)" ::: "memory");                        \
  __builtin_amdgcn_s_barrier();                                             \
  __builtin_amdgcn_sched_barrier(0);

#define DN_TAIL                                                             \
  DN_COMPUTE(o0)                                                            \
  asm volatile("s_waitcnt vmcnt(0)" ::: "memory");                          \
  __builtin_amdgcn_sched_barrier(0);                                        \
  DN_WRITEB(o1, bB)                                                         \
  asm volatile("s_waitcnt lgkmcnt(0)" ::: "memory");                        \
  __builtin_amdgcn_s_barrier();                                             \
  __builtin_amdgcn_sched_barrier(0);                                        \
  DN_COMPUTE(o1)

  if (b < 1024) {
    // ---------------- expert: NT=16 ----------------
    int e = b & 7, nt = (b >> 3) & 31, mt = b >> 8;
    int cnt = counts[e];
    if (mt * 128 >= cnt) return;
    const u16* hb = hbufB + (size_t)e * 524288;

    const u16* aptr[4];
    int aoff[4];
#pragma unroll
    for (int i = 0; i < 4; i++) {
      aptr[i] = hb + (size_t)wv * 8192 +
                (size_t)(mt * 128 + i * 32 + (lane >> 1)) * 16 +
                (((lane & 1) ^ ((lane >> 3) & 1)) * 8);
      aoff[i] = wv * 2048 + i * 512;
    }
    const float* bsrc[4];
    int bwr[4];
#pragma unroll
    for (int i = 0; i < 4; i++) {
      int rloc = wv * 16 + i * 4 + quad;
      bsrc[i] = Wd + (size_t)(e * 2048 + nt * 64 + rloc) * 1024 + l16 * 4;
      bwr[i] = rloc * 64 + (((l16 >> 1) ^ (rloc & 7)) * 8) + ((l16 & 1) * 4);
    }

    f32x4 bA0, bA1, bA2, bA3, bB0, bB1, bB2, bB3;
    f32x4 acc00 = {}, acc01 = {}, acc02 = {}, acc03 = {};
    f32x4 acc10 = {}, acc11 = {}, acc12 = {}, acc13 = {};

    int o0 = 0, o1 = 8192, o2 = 16384;
    DN_PROLOGUE
    for (int kt = 0; kt < 14; kt += 2) {
      DN_PHASE(kt, o0, o2, o1, bA, bB)
      DN_PHASE(kt + 1, o1, o0, o2, bB, bA)
      int tmp = o0; o0 = o2; o2 = o1; o1 = tmp;
    }
    DN_TAIL

#define DE_EPI(ACC, i, n)                                                   \
  _Pragma("unroll") for (int g = 0; g < 4; g++) {                           \
    int sl = mt * 128 + wv * 32 + (i) * 16 + quad * 4 + g;                  \
    if (sl < cnt) {                                                         \
      atomicAdd(&out[(size_t)ptok[(e << 9) + sl] * 2048 + nt * 64 +         \
                     (n) * 16 + l16],                                       \
                pw[(e << 9) + sl] * ACC[g]);                                \
    }                                                                       \
  }
    DE_EPI(acc00, 0, 0) DE_EPI(acc01, 0, 1) DE_EPI(acc02, 0, 2) DE_EPI(acc03, 0, 3)
    DE_EPI(acc10, 1, 0) DE_EPI(acc11, 1, 1) DE_EPI(acc12, 1, 2) DE_EPI(acc13, 1, 3)
#undef DE_EPI
  } else {
    // ---------------- shared: NT=32 ----------------
    int bs = b - 1024;
    int xcd = bs & 7, mt = (bs >> 3) & 3, nt = (bs >> 5) * 8 + xcd;

    const u16* aptr[4];
    int aoff[4];
#pragma unroll
    for (int i = 0; i < 4; i++) {
      aptr[i] = hsB + (size_t)wv * 8192 +
                (size_t)(mt * 128 + i * 32 + (lane >> 1)) * 16 +
                (((lane & 1) ^ ((lane >> 3) & 1)) * 8);
      aoff[i] = wv * 2048 + i * 512;
    }
    const float* bsrc[4];
    int bwr[4];
#pragma unroll
    for (int i = 0; i < 4; i++) {
      int rloc = wv * 16 + i * 4 + quad;
      bsrc[i] = SWd + (size_t)(nt * 64 + rloc) * 2048 + l16 * 4;
      bwr[i] = rloc * 64 + (((l16 >> 1) ^ (rloc & 7)) * 8) + ((l16 & 1) * 4);
    }

    f32x4 bA0, bA1, bA2, bA3, bB0, bB1, bB2, bB3;
    f32x4 acc00 = {}, acc01 = {}, acc02 = {}, acc03 = {};
    f32x4 acc10 = {}, acc11 = {}, acc12 = {}, acc13 = {};

    int o0 = 0, o1 = 8192, o2 = 16384;
    DN_PROLOGUE
    for (int kt = 0; kt < 30; kt += 2) {
      DN_PHASE(kt, o0, o2, o1, bA, bB)
      DN_PHASE(kt + 1, o1, o0, o2, bB, bA)
      int tmp = o0; o0 = o2; o2 = o1; o1 = tmp;
    }
    DN_TAIL

#define DS_EPI(ACC, i, n)                                                   \
  _Pragma("unroll") for (int g = 0; g < 4; g++) {                           \
    int row = mt * 128 + wv * 32 + (i) * 16 + quad * 4 + g;                 \
    atomicAdd(&out[(size_t)row * 2048 + nt * 64 + (n) * 16 + l16],          \
              sgate[row] * ACC[g]);                                         \
  }
    DS_EPI(acc00, 0, 0) DS_EPI(acc01, 0, 1) DS_EPI(acc02, 0, 2) DS_EPI(acc03, 0, 3)
    DS_EPI(acc10, 1, 0) DS_EPI(acc11, 1, 1) DS_EPI(acc12, 1, 2) DS_EPI(acc13, 1, 3)
#undef DS_EPI
  }
#undef DN_ISSUE
#undef DN_WRITEB
#undef DN_COMPUTE
#undef DN_PHASE
#undef DN_PROLOGUE
#undef DN_TAIL
}

extern "C" void kernel_launch(void* const* d_in, const int* in_sizes, int n_in,
                              void* d_out, int out_size, void* d_ws, size_t ws_size,
                              hipStream_t stream) {
  const float* x = (const float*)d_in[0];
  const float* gate_w = (const float*)d_in[1];
  const float* w_gate = (const float*)d_in[2];
  const float* w_up = (const float*)d_in[3];
  const float* w_down = (const float*)d_in[4];
  const float* sh_gate = (const float*)d_in[5];
  const float* sh_up = (const float*)d_in[6];
  const float* sh_down = (const float*)d_in[7];
  const float* se_gate_w = (const float*)d_in[8];
  float* out = (float*)d_out;

  char* ws = (char*)d_ws;
  int* counts = (int*)(ws + 0);                       // 32 B
  int* ptok = (int*)(ws + 1024);                      // 16 KB
  float* pw = (float*)(ws + 1024 + 16384);            // 16 KB
  float* sg = (float*)(ws + 1024 + 32768);            // 2 KB
  u16* xb = (u16*)(ws + 65536);                       // 2 MB
  u16* hbufB = (u16*)(ws + 65536 + (2u << 20));       // [e][j16][512][16] = 8 MB
  u16* hsB = (u16*)(ws + 65536 + (10u << 20));        // [j16][512][16] = 2 MB

  hipMemsetAsync(counts, 0, 32, stream);
  hipMemsetAsync(out, 0, out_size, stream);
  route_prep_kernel<<<512, 64, 0, stream>>>(x, gate_w, se_gate_w, counts,
                                            ptok, pw, sg, xb);
  // gateup: expert 8e*32j*4mt = 1024 (live ~400) + shared 256
  gateup_kernel<<<1280, 256, 0, stream>>>(xb, w_gate, w_up, sh_gate, sh_up,
                                          hbufB, hsB, ptok, counts);
  // merged down: expert 1024 (live ~400) + shared 128, atomicAdd on zeroed out
  down_kernel<<<1152, 256, 0, stream>>>(hbufB, hsB, w_down, sh_down, out,
                                        ptok, pw, counts, sg);
}

// Round 8
// 315.405 us; speedup vs baseline: 1.1217x; 1.1217x over previous
//
#include <hip/hip_runtime.h>

typedef unsigned short u16;
typedef u16 u16x8 __attribute__((ext_vector_type(8)));
typedef __bf16 bf16x8 __attribute__((ext_vector_type(8)));
typedef float f32x4 __attribute__((ext_vector_type(4)));

#define NE 8

// ---- helpers ----
__device__ __forceinline__ unsigned pk2(float a, float b) {
  unsigned ua = __builtin_bit_cast(unsigned, a) + 0x8000u;
  unsigned ub = __builtin_bit_cast(unsigned, b) + 0x8000u;
  return __builtin_amdgcn_perm(ub, ua, 0x07060302);
}
__device__ __forceinline__ u16 f2bf(float f) {
  return (u16)((__builtin_bit_cast(unsigned, f) + 0x8000u) >> 16);
}
__device__ __forceinline__ bf16x8 ldfrag(const u16* p) {
  union { u16x8 u; bf16x8 b; } x;
  x.u = *(const u16x8*)p;
  return x.b;
}
// async global->LDS, 16 B/lane: HW writes lane l at (uniform lds base) + l*16
__device__ __forceinline__ void gld16(const void* g, void* l) {
  __builtin_amdgcn_global_load_lds(
      (const __attribute__((address_space(1))) unsigned int*)g,
      (__attribute__((address_space(3))) unsigned int*)l, 16, 0, 0);
}
#define MFMA16 __builtin_amdgcn_mfma_f32_16x16x32_bf16

// ---- fused routing + x->bf16 prep ----
__global__ __launch_bounds__(64) void route_prep_kernel(
    const float* __restrict__ x, const float* __restrict__ gw,
    const float* __restrict__ segw, int* __restrict__ counts,
    int* __restrict__ ptok, float* __restrict__ pw, float* __restrict__ sgate,
    u16* __restrict__ xb) {
  int t = blockIdx.x;
  int lane = threadIdx.x;
  const float* xr = x + (size_t)t * 2048;
  u16* xbr = xb + (size_t)t * 2048;
  float s[NE];
#pragma unroll
  for (int e = 0; e < NE; e++) s[e] = 0.f;
  float sg = 0.f;
#pragma unroll
  for (int it = 0; it < 8; it++) {
    int c = it * 256 + lane * 4;
    f32x4 xv = *(const f32x4*)(xr + c);
    *(uint2*)(xbr + c) = make_uint2(pk2(xv[0], xv[1]), pk2(xv[2], xv[3]));
#pragma unroll
    for (int e = 0; e < NE; e++) {
      f32x4 wv4 = *(const f32x4*)(gw + e * 2048 + c);
      s[e] += xv[0] * wv4[0] + xv[1] * wv4[1] + xv[2] * wv4[2] + xv[3] * wv4[3];
    }
    f32x4 sv = *(const f32x4*)(segw + c);
    sg += xv[0] * sv[0] + xv[1] * sv[1] + xv[2] * sv[2] + xv[3] * sv[3];
  }
#pragma unroll
  for (int off = 32; off > 0; off >>= 1) {
#pragma unroll
    for (int e = 0; e < NE; e++) s[e] += __shfl_down(s[e], off);
    sg += __shfl_down(sg, off);
  }
  if (lane == 0) {
    int i0 = 0;
#pragma unroll
    for (int e = 1; e < NE; e++) if (s[e] > s[i0]) i0 = e;
    int i1 = (i0 == 0) ? 1 : 0;
#pragma unroll
    for (int e = 0; e < NE; e++) if (e != i0 && s[e] > s[i1]) i1 = e;
    float r = __expf(s[i1] - s[i0]);
    float w0 = 1.f / (1.f + r);
    float w1 = 1.f - w0;
    int s0 = atomicAdd(&counts[i0], 1);
    ptok[(i0 << 9) + s0] = t; pw[(i0 << 9) + s0] = w0;
    int s1 = atomicAdd(&counts[i1], 1);
    ptok[(i1 << 9) + s1] = t; pw[(i1 << 9) + s1] = w1;
    sgate[t] = 1.f / (1.f + __expf(-sg));
  }
}

// ====== gateup: M=128, N=64 (32 gate + 32 up), BK=64, K=2048 ======
// R5-verified schedule (ISSUE -> COMPUTE -> FINISH, 2 LDS buffers) at N=64.
// K-loop START IS STAGGERED per block (kidx rotation) to break the chip-wide
// phase-lock that pinned per-step time at ~3.3us regardless of structure.
__global__ __launch_bounds__(256) void gateup_kernel(
    const u16* __restrict__ xb, const float* __restrict__ Wg,
    const float* __restrict__ Wu, const float* __restrict__ SWg,
    const float* __restrict__ SWu, u16* __restrict__ hbufB,
    u16* __restrict__ hsB, const int* __restrict__ ptok,
    const int* __restrict__ counts) {
  __shared__ __align__(16) u16 As[2 * 8192];  // 2 x 16 KB (128x64 bf16)
  __shared__ __align__(16) u16 Bs[2 * 4096];  // 2 x 8 KB  (64x64 bf16)

  int b = blockIdx.x;
  int t = threadIdx.x;
  int is_ex = (b < 1024);
  int e = 0, j, mt, cnt;
  const float *gW, *uW;
  u16* obase;
  if (is_ex) {
    e = b & 7; j = (b >> 3) & 31; mt = b >> 8;  // 8e x 32j x 4mt
    cnt = counts[e];
    if (mt * 128 >= cnt) return;
    gW = Wg + (size_t)(e * 1024 + j * 32) * 2048;
    uW = Wu + (size_t)(e * 1024 + j * 32) * 2048;
    obase = hbufB + (size_t)(e * 64 + 2 * j) * 8192;
  } else {
    // shared: 64j x 4mt, same-j pinned to one XCD
    int bs = b - 1024;
    int xcd = bs & 7; mt = (bs >> 3) & 3; j = (bs >> 5) * 8 + xcd; cnt = 512;
    gW = SWg + (size_t)(j * 32) * 2048;
    uW = SWu + (size_t)(j * 32) * 2048;
    obase = hsB + (size_t)(2 * j) * 8192;
  }

  int lane = t & 63, wv = t >> 6;
  int quad = lane >> 4, l16 = lane & 15;
  int kt0 = (b * 11) & 31;  // stagger

  // A: 16 chunks of 8 rows x 128 B; wave wv stages chunks 4wv..4wv+3
  const u16* aptr[4];
  int aoff[4];
#pragma unroll
  for (int i = 0; i < 4; i++) {
    int c = 4 * wv + i;
    int row = 8 * c + (lane >> 3);
    int slot = mt * 128 + row;
    int tok = is_ex ? ((slot < cnt) ? ptok[(e << 9) + slot] : 0) : slot;
    aptr[i] = xb + (size_t)tok * 2048 + (((lane & 7) ^ ((lane >> 3) & 7)) * 8);
    aoff[i] = c * 512;
  }
  // B: 64 rows (32 gate + 32 up); thread stages 4 rows: rloc = wv*16+i*4+quad
  const float* bsrc[4];
  int bwr[4];
#pragma unroll
  for (int i = 0; i < 4; i++) {
    int rloc = wv * 16 + i * 4 + quad;
    const float* base = (rloc < 32) ? (gW + (size_t)rloc * 2048)
                                    : (uW + (size_t)(rloc - 32) * 2048);
    bsrc[i] = base + l16 * 4;
    bwr[i] = rloc * 64 + (((l16 >> 1) ^ (rloc & 7)) * 8) + ((l16 & 1) * 4);
  }

  f32x4 bv0, bv1, bv2, bv3;
  f32x4 acc00 = {}, acc01 = {}, acc02 = {}, acc03 = {};
  f32x4 acc10 = {}, acc11 = {}, acc12 = {}, acc13 = {};

#define GU_ISSUE(kk, ao)                                                    \
  bv0 = *(const f32x4*)(bsrc[0] + (kk) * 64);                               \
  bv1 = *(const f32x4*)(bsrc[1] + (kk) * 64);                               \
  bv2 = *(const f32x4*)(bsrc[2] + (kk) * 64);                               \
  bv3 = *(const f32x4*)(bsrc[3] + (kk) * 64);                               \
  gld16(aptr[0] + (kk) * 64, &As[(ao) + aoff[0]]);                          \
  gld16(aptr[1] + (kk) * 64, &As[(ao) + aoff[1]]);                          \
  gld16(aptr[2] + (kk) * 64, &As[(ao) + aoff[2]]);                          \
  gld16(aptr[3] + (kk) * 64, &As[(ao) + aoff[3]]);                          \
  __builtin_amdgcn_sched_barrier(0);

#define GU_FINISH(ao)                                                       \
  asm volatile("s_waitcnt vmcnt(4)" ::: "memory");                          \
  __builtin_amdgcn_sched_barrier(0);                                        \
  *(uint2*)(&Bs[((ao) >> 1) + bwr[0]]) =                                    \
      make_uint2(pk2(bv0[0], bv0[1]), pk2(bv0[2], bv0[3]));                 \
  *(uint2*)(&Bs[((ao) >> 1) + bwr[1]]) =                                    \
      make_uint2(pk2(bv1[0], bv1[1]), pk2(bv1[2], bv1[3]));                 \
  *(uint2*)(&Bs[((ao) >> 1) + bwr[2]]) =                                    \
      make_uint2(pk2(bv2[0], bv2[1]), pk2(bv2[2], bv2[3]));                 \
  *(uint2*)(&Bs[((ao) >> 1) + bwr[3]]) =                                    \
      make_uint2(pk2(bv3[0], bv3[1]), pk2(bv3[2], bv3[3]));                 \
  asm volatile("s_waitcnt vmcnt(0) lgkmcnt(0)" ::: "memory");               \
  __builtin_amdgcn_s_barrier();                                             \
  __builtin_amdgcn_sched_barrier(0);

#define GU_COMPUTE(ao)                                                      \
  _Pragma("unroll") for (int k2 = 0; k2 < 2; k2++) {                        \
    int sl = ((k2 * 4 + quad) ^ (l16 & 7)) * 8;                             \
    bf16x8 af0 = ldfrag(&As[(ao) + (wv * 32 + l16) * 64 + sl]);             \
    bf16x8 af1 = ldfrag(&As[(ao) + (wv * 32 + 16 + l16) * 64 + sl]);        \
    bf16x8 bf0 = ldfrag(&Bs[((ao) >> 1) + l16 * 64 + sl]);                  \
    bf16x8 bf1 = ldfrag(&Bs[((ao) >> 1) + (16 + l16) * 64 + sl]);           \
    bf16x8 bf2 = ldfrag(&Bs[((ao) >> 1) + (32 + l16) * 64 + sl]);           \
    bf16x8 bf3 = ldfrag(&Bs[((ao) >> 1) + (48 + l16) * 64 + sl]);           \
    acc00 = MFMA16(af0, bf0, acc00, 0, 0, 0);                               \
    acc01 = MFMA16(af0, bf1, acc01, 0, 0, 0);                               \
    acc02 = MFMA16(af0, bf2, acc02, 0, 0, 0);                               \
    acc03 = MFMA16(af0, bf3, acc03, 0, 0, 0);                               \
    acc10 = MFMA16(af1, bf0, acc10, 0, 0, 0);                               \
    acc11 = MFMA16(af1, bf1, acc11, 0, 0, 0);                               \
    acc12 = MFMA16(af1, bf2, acc12, 0, 0, 0);                               \
    acc13 = MFMA16(af1, bf3, acc13, 0, 0, 0);                               \
  }

  GU_ISSUE(kt0, 0);
  GU_FINISH(0);
  for (int kt = 0; kt < 32; kt++) {
    int ao0 = (kt & 1) * 8192, ao1 = 8192 - ao0;
    if (kt < 31) { GU_ISSUE((kt + 1 + kt0) & 31, ao1); }
    GU_COMPUTE(ao0);
    if (kt < 31) { GU_FINISH(ao1); }
  }
#undef GU_ISSUE
#undef GU_FINISH
#undef GU_COMPUTE

  // epilogue: h = silu(g)*u ; gate frag n pairs with up frag n+2
#define GU_EPI(AG, AU, i, n)                                                \
  _Pragma("unroll") for (int g = 0; g < 4; g++) {                           \
    int rloc = wv * 32 + (i) * 16 + quad * 4 + g;                           \
    int slot = mt * 128 + rloc;                                             \
    if (slot < cnt) {                                                       \
      float gv = AG[g], uv = AU[g];                                         \
      float h = gv / (1.f + __expf(-gv)) * uv;                              \
      obase[(size_t)(n) * 8192 + slot * 16 + l16] = f2bf(h);                \
    }                                                                       \
  }
  GU_EPI(acc00, acc02, 0, 0)
  GU_EPI(acc01, acc03, 0, 1)
  GU_EPI(acc10, acc12, 1, 0)
  GU_EPI(acc11, acc13, 1, 1)
#undef GU_EPI
}

// ====== merged down: expert [0,1024) M=128 N=64 K=1024; ======
// ====== shared [1024,1152) M=128 N=64 K=2048; staggered K-loop ======
__global__ __launch_bounds__(256) void down_kernel(
    const u16* __restrict__ hbufB, const u16* __restrict__ hsB,
    const float* __restrict__ Wd, const float* __restrict__ SWd,
    float* __restrict__ out, const int* __restrict__ ptok,
    const float* __restrict__ pw, const int* __restrict__ counts,
    const float* __restrict__ sgate) {
  __shared__ __align__(16) u16 As[2 * 8192];  // 2 x 16 KB (4 j16-groups)
  __shared__ __align__(16) u16 Bs[2 * 4096];  // 2 x 8 KB

  int b = blockIdx.x;
  int t = threadIdx.x;
  int lane = t & 63, wv = t >> 6;
  int quad = lane >> 4, l16 = lane & 15;

  f32x4 bv0, bv1, bv2, bv3;
  f32x4 acc00 = {}, acc01 = {}, acc02 = {}, acc03 = {};
  f32x4 acc10 = {}, acc11 = {}, acc12 = {}, acc13 = {};

#define DN_ISSUE(kk, ao)                                                    \
  bv0 = *(const f32x4*)(bsrc[0] + (kk) * 64);                               \
  bv1 = *(const f32x4*)(bsrc[1] + (kk) * 64);                               \
  bv2 = *(const f32x4*)(bsrc[2] + (kk) * 64);                               \
  bv3 = *(const f32x4*)(bsrc[3] + (kk) * 64);                               \
  gld16(aptr[0] + (size_t)(kk) * 32768, &As[(ao) + aoff[0]]);               \
  gld16(aptr[1] + (size_t)(kk) * 32768, &As[(ao) + aoff[1]]);               \
  gld16(aptr[2] + (size_t)(kk) * 32768, &As[(ao) + aoff[2]]);               \
  gld16(aptr[3] + (size_t)(kk) * 32768, &As[(ao) + aoff[3]]);               \
  __builtin_amdgcn_sched_barrier(0);

#define DN_FINISH(ao)                                                       \
  asm volatile("s_waitcnt vmcnt(4)" ::: "memory");                          \
  __builtin_amdgcn_sched_barrier(0);                                        \
  *(uint2*)(&Bs[((ao) >> 1) + bwr[0]]) =                                    \
      make_uint2(pk2(bv0[0], bv0[1]), pk2(bv0[2], bv0[3]));                 \
  *(uint2*)(&Bs[((ao) >> 1) + bwr[1]]) =                                    \
      make_uint2(pk2(bv1[0], bv1[1]), pk2(bv1[2], bv1[3]));                 \
  *(uint2*)(&Bs[((ao) >> 1) + bwr[2]]) =                                    \
      make_uint2(pk2(bv2[0], bv2[1]), pk2(bv2[2], bv2[3]));                 \
  *(uint2*)(&Bs[((ao) >> 1) + bwr[3]]) =                                    \
      make_uint2(pk2(bv3[0], bv3[1]), pk2(bv3[2], bv3[3]));                 \
  asm volatile("s_waitcnt vmcnt(0) lgkmcnt(0)" ::: "memory");               \
  __builtin_amdgcn_s_barrier();                                             \
  __builtin_amdgcn_sched_barrier(0);

#define DN_COMPUTE(ao)                                                      \
  _Pragma("unroll") for (int k2 = 0; k2 < 2; k2++) {                        \
    int jsec = (k2 * 2 + (quad >> 1)) * 2048 +                              \
               (((quad & 1) ^ ((l16 >> 2) & 1)) * 8);                       \
    int sl = ((k2 * 4 + quad) ^ (l16 & 7)) * 8;                             \
    bf16x8 af0 = ldfrag(&As[(ao) + jsec + (wv * 32 + l16) * 16]);           \
    bf16x8 af1 = ldfrag(&As[(ao) + jsec + (wv * 32 + 16 + l16) * 16]);      \
    bf16x8 bf0 = ldfrag(&Bs[((ao) >> 1) + l16 * 64 + sl]);                  \
    bf16x8 bf1 = ldfrag(&Bs[((ao) >> 1) + (16 + l16) * 64 + sl]);           \
    bf16x8 bf2 = ldfrag(&Bs[((ao) >> 1) + (32 + l16) * 64 + sl]);           \
    bf16x8 bf3 = ldfrag(&Bs[((ao) >> 1) + (48 + l16) * 64 + sl]);           \
    acc00 = MFMA16(af0, bf0, acc00, 0, 0, 0);                               \
    acc01 = MFMA16(af0, bf1, acc01, 0, 0, 0);                               \
    acc02 = MFMA16(af0, bf2, acc02, 0, 0, 0);                               \
    acc03 = MFMA16(af0, bf3, acc03, 0, 0, 0);                               \
    acc10 = MFMA16(af1, bf0, acc10, 0, 0, 0);                               \
    acc11 = MFMA16(af1, bf1, acc11, 0, 0, 0);                               \
    acc12 = MFMA16(af1, bf2, acc12, 0, 0, 0);                               \
    acc13 = MFMA16(af1, bf3, acc13, 0, 0, 0);                               \
  }

  if (b < 1024) {
    // ---------------- expert: M=128 N=64 K=1024 (16 steps) ----------------
    int e = b & 7, nt = (b >> 3) & 31, mt = b >> 8;
    int cnt = counts[e];
    if (mt * 128 >= cnt) return;
    const u16* hb = hbufB + (size_t)e * 524288;
    int kt0 = (b * 11) & 15;

    const u16* aptr[4];
    int aoff[4];
#pragma unroll
    for (int i = 0; i < 4; i++) {
      aptr[i] = hb + (size_t)wv * 8192 +
                (size_t)(mt * 128 + i * 32 + (lane >> 1)) * 16 +
                (((lane & 1) ^ ((lane >> 3) & 1)) * 8);
      aoff[i] = wv * 2048 + i * 512;
    }
    const float* bsrc[4];
    int bwr[4];
#pragma unroll
    for (int i = 0; i < 4; i++) {
      int rloc = wv * 16 + i * 4 + quad;
      bsrc[i] = Wd + (size_t)(e * 2048 + nt * 64 + rloc) * 1024 + l16 * 4;
      bwr[i] = rloc * 64 + (((l16 >> 1) ^ (rloc & 7)) * 8) + ((l16 & 1) * 4);
    }

    DN_ISSUE(kt0, 0);
    DN_FINISH(0);
    for (int kt = 0; kt < 16; kt++) {
      int ao0 = (kt & 1) * 8192, ao1 = 8192 - ao0;
      if (kt < 15) { DN_ISSUE((kt + 1 + kt0) & 15, ao1); }
      DN_COMPUTE(ao0);
      if (kt < 15) { DN_FINISH(ao1); }
    }

#define DE_EPI(ACC, i, n)                                                   \
  _Pragma("unroll") for (int g = 0; g < 4; g++) {                           \
    int sl = mt * 128 + wv * 32 + (i) * 16 + quad * 4 + g;                  \
    if (sl < cnt) {                                                         \
      atomicAdd(&out[(size_t)ptok[(e << 9) + sl] * 2048 + nt * 64 +         \
                     (n) * 16 + l16],                                       \
                pw[(e << 9) + sl] * ACC[g]);                                \
    }                                                                       \
  }
    DE_EPI(acc00, 0, 0) DE_EPI(acc01, 0, 1) DE_EPI(acc02, 0, 2) DE_EPI(acc03, 0, 3)
    DE_EPI(acc10, 1, 0) DE_EPI(acc11, 1, 1) DE_EPI(acc12, 1, 2) DE_EPI(acc13, 1, 3)
#undef DE_EPI
  } else {
    // ---------------- shared: M=128 N=64 K=2048 (32 steps) ----------------
    int bs = b - 1024;
    int xcd = bs & 7, mt = (bs >> 3) & 3, nt = (bs >> 5) * 8 + xcd;
    int kt0 = (b * 11) & 31;

    const u16* aptr[4];
    int aoff[4];
#pragma unroll
    for (int i = 0; i < 4; i++) {
      aptr[i] = hsB + (size_t)wv * 8192 +
                (size_t)(mt * 128 + i * 32 + (lane >> 1)) * 16 +
                (((lane & 1) ^ ((lane >> 3) & 1)) * 8);
      aoff[i] = wv * 2048 + i * 512;
    }
    const float* bsrc[4];
    int bwr[4];
#pragma unroll
    for (int i = 0; i < 4; i++) {
      int rloc = wv * 16 + i * 4 + quad;
      bsrc[i] = SWd + (size_t)(nt * 64 + rloc) * 2048 + l16 * 4;
      bwr[i] = rloc * 64 + (((l16 >> 1) ^ (rloc & 7)) * 8) + ((l16 & 1) * 4);
    }

    DN_ISSUE(kt0, 0);
    DN_FINISH(0);
    for (int kt = 0; kt < 32; kt++) {
      int ao0 = (kt & 1) * 8192, ao1 = 8192 - ao0;
      if (kt < 31) { DN_ISSUE((kt + 1 + kt0) & 31, ao1); }
      DN_COMPUTE(ao0);
      if (kt < 31) { DN_FINISH(ao1); }
    }

#define DS_EPI(ACC, i, n)                                                   \
  _Pragma("unroll") for (int g = 0; g < 4; g++) {                           \
    int row = mt * 128 + wv * 32 + (i) * 16 + quad * 4 + g;                 \
    atomicAdd(&out[(size_t)row * 2048 + nt * 64 + (n) * 16 + l16],          \
              sgate[row] * ACC[g]);                                         \
  }
    DS_EPI(acc00, 0, 0) DS_EPI(acc01, 0, 1) DS_EPI(acc02, 0, 2) DS_EPI(acc03, 0, 3)
    DS_EPI(acc10, 1, 0) DS_EPI(acc11, 1, 1) DS_EPI(acc12, 1, 2) DS_EPI(acc13, 1, 3)
#undef DS_EPI
  }
#undef DN_ISSUE
#undef DN_FINISH
#undef DN_COMPUTE
}

extern "C" void kernel_launch(void* const* d_in, const int* in_sizes, int n_in,
                              void* d_out, int out_size, void* d_ws, size_t ws_size,
                              hipStream_t stream) {
  const float* x = (const float*)d_in[0];
  const float* gate_w = (const float*)d_in[1];
  const float* w_gate = (const float*)d_in[2];
  const float* w_up = (const float*)d_in[3];
  const float* w_down = (const float*)d_in[4];
  const float* sh_gate = (const float*)d_in[5];
  const float* sh_up = (const float*)d_in[6];
  const float* sh_down = (const float*)d_in[7];
  const float* se_gate_w = (const float*)d_in[8];
  float* out = (float*)d_out;

  char* ws = (char*)d_ws;
  int* counts = (int*)(ws + 0);                       // 32 B
  int* ptok = (int*)(ws + 1024);                      // 16 KB
  float* pw = (float*)(ws + 1024 + 16384);            // 16 KB
  float* sg = (float*)(ws + 1024 + 32768);            // 2 KB
  u16* xb = (u16*)(ws + 65536);                       // 2 MB
  u16* hbufB = (u16*)(ws + 65536 + (2u << 20));       // [e][j16][512][16] = 8 MB
  u16* hsB = (u16*)(ws + 65536 + (10u << 20));        // [j16][512][16] = 2 MB

  hipMemsetAsync(counts, 0, 32, stream);
  hipMemsetAsync(out, 0, out_size, stream);
  route_prep_kernel<<<512, 64, 0, stream>>>(x, gate_w, se_gate_w, counts,
                                            ptok, pw, sg, xb);
  // gateup: expert 8e*32j*4mt = 1024 (live 256) + shared 256
  gateup_kernel<<<1280, 256, 0, stream>>>(xb, w_gate, w_up, sh_gate, sh_up,
                                          hbufB, hsB, ptok, counts);
  // merged down: expert 1024 (live 256) + shared 128, atomicAdd on zeroed out
  down_kernel<<<1152, 256, 0, stream>>>(hbufB, hsB, w_down, sh_down, out,
                                        ptok, pw, counts, sg);
}